// Round 2
// baseline (1124.182 us; speedup 1.0000x reference)
//
#include <hip/hip_runtime.h>
#include <hip/hip_bf16.h>

#define D_MODEL 1024
#define HEAD    64
#define SEQ     2048
#define BATCH   4
#define ROWS    (BATCH * SEQ)   // 8192

// ---------------------------------------------------------------------------
// Kernel 1: fused QKV projection.  x:[8192,1024] f32, W*:[1024,64], b*:[64]
// -> q,k,v [8192,64] f32 in workspace.
// v2: W tiles staged in LDS (wave-broadcast reads), double-buffered with
// reg-staged global loads issued before compute; one barrier per K-tile.
// Block: 256 thr, 32 rows x 192 cols, 24 fp32 acc/thread. Grid 256.
// ---------------------------------------------------------------------------
__global__ __launch_bounds__(256) void qkv_proj(
    const float* __restrict__ x,
    const float* __restrict__ Wq, const float* __restrict__ bq,
    const float* __restrict__ Wk, const float* __restrict__ bk,
    const float* __restrict__ Wv, const float* __restrict__ bv,
    float* __restrict__ q, float* __restrict__ k, float* __restrict__ v)
{
    __shared__ float Xs[2][32][68];     // 17.4 KB  (stride 68: 16B-aligned)
    __shared__ float Ws[2][64][192];    // 96 KB    (row = one k, cols q|k|v)

    const int tid  = threadIdx.x;
    const int row0 = blockIdx.x * 32;
    const int tr   = tid >> 4;          // rows 2*tr, 2*tr+1
    const int tc   = tid & 15;          // cols 4*tc..4*tc+3 per matrix

    const int xlr = tid >> 3;           // X staging: row 0..31
    const int xlc = (tid & 7) * 8;      // X staging: col 0,8,..,56

    const float* wbase[3] = {Wq, Wk, Wv};

    float aq[2][4] = {}, ak[2][4] = {}, av[2][4] = {};
    float4 xr[2];
    float4 wr[3][4];

    // ---- stage helpers (inlined manually) ----
    // load tile k0 into regs
    auto load_stage = [&](int k0) {
        const float* xs = x + (size_t)(row0 + xlr) * D_MODEL + k0 + xlc;
        xr[0] = *(const float4*)(xs);
        xr[1] = *(const float4*)(xs + 4);
        #pragma unroll
        for (int m = 0; m < 3; ++m) {
            const float* wt = wbase[m] + (size_t)k0 * HEAD;   // tile is contiguous
            #pragma unroll
            for (int i = 0; i < 4; ++i)
                wr[m][i] = *(const float4*)(wt + (i * 256 + tid) * 4);
        }
    };
    auto store_stage = [&](int buf) {
        *(float4*)&Xs[buf][xlr][xlc]     = xr[0];
        *(float4*)&Xs[buf][xlr][xlc + 4] = xr[1];
        #pragma unroll
        for (int m = 0; m < 3; ++m) {
            #pragma unroll
            for (int i = 0; i < 4; ++i) {
                const int idx = i * 256 + tid;
                Ws[buf][idx >> 4][m * 64 + (idx & 15) * 4 + 0] = 0.0f; // placeholder overwritten below
                *(float4*)&Ws[buf][idx >> 4][m * 64 + (idx & 15) * 4] = wr[m][i];
            }
        }
    };
    auto compute = [&](int buf) {
        #pragma unroll
        for (int kk = 0; kk < 64; kk += 4) {
            float4 xa = *(const float4*)&Xs[buf][2 * tr][kk];
            float4 xb = *(const float4*)&Xs[buf][2 * tr + 1][kk];
            float xs0[4] = {xa.x, xa.y, xa.z, xa.w};
            float xs1[4] = {xb.x, xb.y, xb.z, xb.w};
            #pragma unroll
            for (int u = 0; u < 4; ++u) {
                float4 wq4 = *(const float4*)&Ws[buf][kk + u][tc * 4];
                float4 wk4 = *(const float4*)&Ws[buf][kk + u][64 + tc * 4];
                float4 wv4 = *(const float4*)&Ws[buf][kk + u][128 + tc * 4];
                aq[0][0] += xs0[u]*wq4.x; aq[0][1] += xs0[u]*wq4.y;
                aq[0][2] += xs0[u]*wq4.z; aq[0][3] += xs0[u]*wq4.w;
                aq[1][0] += xs1[u]*wq4.x; aq[1][1] += xs1[u]*wq4.y;
                aq[1][2] += xs1[u]*wq4.z; aq[1][3] += xs1[u]*wq4.w;
                ak[0][0] += xs0[u]*wk4.x; ak[0][1] += xs0[u]*wk4.y;
                ak[0][2] += xs0[u]*wk4.z; ak[0][3] += xs0[u]*wk4.w;
                ak[1][0] += xs1[u]*wk4.x; ak[1][1] += xs1[u]*wk4.y;
                ak[1][2] += xs1[u]*wk4.z; ak[1][3] += xs1[u]*wk4.w;
                av[0][0] += xs0[u]*wv4.x; av[0][1] += xs0[u]*wv4.y;
                av[0][2] += xs0[u]*wv4.z; av[0][3] += xs0[u]*wv4.w;
                av[1][0] += xs1[u]*wv4.x; av[1][1] += xs1[u]*wv4.y;
                av[1][2] += xs1[u]*wv4.z; av[1][3] += xs1[u]*wv4.w;
            }
        }
    };

    // ---- pipeline: load(0) -> store(0) -> [load(t+1) | compute(t) | store] ----
    load_stage(0);
    store_stage(0);
    __syncthreads();
    int cur = 0;
    for (int t = 0; t < 16; ++t) {
        if (t < 15) load_stage((t + 1) * 64);    // issue globals early
        compute(cur);
        if (t < 15) {
            store_stage(cur ^ 1);                 // write other buffer
            __syncthreads();
            cur ^= 1;
        }
    }

    // ---- epilogue: bias + store ----
    float4 bq4 = *(const float4*)(bq + tc * 4);
    float4 bk4 = *(const float4*)(bk + tc * 4);
    float4 bv4 = *(const float4*)(bv + tc * 4);
    #pragma unroll
    for (int i = 0; i < 2; ++i) {
        const size_t row = (size_t)(row0 + 2 * tr + i);
        float4 oq = {aq[i][0] + bq4.x, aq[i][1] + bq4.y, aq[i][2] + bq4.z, aq[i][3] + bq4.w};
        float4 ok = {ak[i][0] + bk4.x, ak[i][1] + bk4.y, ak[i][2] + bk4.z, ak[i][3] + bk4.w};
        float4 ov = {av[i][0] + bv4.x, av[i][1] + bv4.y, av[i][2] + bv4.z, av[i][3] + bv4.w};
        *(float4*)(q + row * HEAD + tc * 4) = oq;
        *(float4*)(k + row * HEAD + tc * 4) = ok;
        *(float4*)(v + row * HEAD + tc * 4) = ov;
    }
}

// ---------------------------------------------------------------------------
// Kernel 2: causal flash attention, fp32 vector-ALU version (unchanged R1).
// ---------------------------------------------------------------------------
__device__ __forceinline__ int kswz(int row, int d) {
    return ((((d >> 2) ^ (row >> 3)) & 15) << 2) | (d & 3);
}

__global__ __launch_bounds__(256) void attn_fwd(
    const float* __restrict__ q, const float* __restrict__ k,
    const float* __restrict__ v, float* __restrict__ out)
{
    __shared__ float Qs[32][68];
    __shared__ float Ks[64][64];   // swizzled
    __shared__ float Vs[64][64];
    __shared__ float Ps[32][68];

    const int tid = threadIdx.x;
    const int b   = blockIdx.y;
    const int q0  = blockIdx.x * 32;
    const int r   = tid >> 3;
    const int sub = tid & 7;

    const float* qb = q + (size_t)b * SEQ * HEAD;
    const float* kb = k + (size_t)b * SEQ * HEAD;
    const float* vb = v + (size_t)b * SEQ * HEAD;

    {
        const float* src = qb + (size_t)(q0 + r) * HEAD + sub * 8;
        #pragma unroll
        for (int u = 0; u < 8; ++u) Qs[r][sub * 8 + u] = src[u] * 0.125f;
    }

    float m = -3.0e38f, l = 0.0f;
    float acc[8] = {};

    const int ntiles = ((q0 + 31) >> 6) + 1;
    const int qrow   = q0 + r;

    for (int t = 0; t < ntiles; ++t) {
        const int kv0 = t * 64;

        __syncthreads();
        {
            const int krow = tid >> 3;
            const int c    = (tid & 7) * 8;
            const float* ksrc0 = kb + (size_t)(kv0 + krow)      * HEAD + c;
            const float* ksrc1 = kb + (size_t)(kv0 + krow + 32) * HEAD + c;
            const float* vsrc0 = vb + (size_t)(kv0 + krow)      * HEAD + c;
            const float* vsrc1 = vb + (size_t)(kv0 + krow + 32) * HEAD + c;
            float4 k00 = *(const float4*)(ksrc0);
            float4 k01 = *(const float4*)(ksrc0 + 4);
            float4 k10 = *(const float4*)(ksrc1);
            float4 k11 = *(const float4*)(ksrc1 + 4);
            *(float4*)&Ks[krow][kswz(krow, c)]             = k00;
            *(float4*)&Ks[krow][kswz(krow, c + 4)]         = k01;
            *(float4*)&Ks[krow + 32][kswz(krow + 32, c)]   = k10;
            *(float4*)&Ks[krow + 32][kswz(krow + 32, c+4)] = k11;
            *(float4*)&Vs[krow][c]          = *(const float4*)(vsrc0);
            *(float4*)&Vs[krow][c + 4]      = *(const float4*)(vsrc0 + 4);
            *(float4*)&Vs[krow + 32][c]     = *(const float4*)(vsrc1);
            *(float4*)&Vs[krow + 32][c + 4] = *(const float4*)(vsrc1 + 4);
        }
        __syncthreads();

        float s[8] = {};
        #pragma unroll
        for (int d = 0; d < 64; d += 4) {
            float4 q4 = *(const float4*)&Qs[r][d];
            #pragma unroll
            for (int jj = 0; jj < 8; ++jj) {
                const int row = sub * 8 + jj;
                float4 k4 = *(const float4*)&Ks[row][kswz(row, d)];
                s[jj] += q4.x*k4.x + q4.y*k4.y + q4.z*k4.z + q4.w*k4.w;
            }
        }

        const bool full = (kv0 + 63 <= q0);
        if (!full) {
            #pragma unroll
            for (int jj = 0; jj < 8; ++jj)
                if (kv0 + sub * 8 + jj > qrow) s[jj] = -3.0e38f;
        }

        float tm = s[0];
        #pragma unroll
        for (int jj = 1; jj < 8; ++jj) tm = fmaxf(tm, s[jj]);
        tm = fmaxf(tm, __shfl_xor(tm, 1, 64));
        tm = fmaxf(tm, __shfl_xor(tm, 2, 64));
        tm = fmaxf(tm, __shfl_xor(tm, 4, 64));

        const float mnew = fmaxf(m, tm);
        const float corr = __expf(m - mnew);
        float p[8], psum = 0.0f;
        #pragma unroll
        for (int jj = 0; jj < 8; ++jj) { p[jj] = __expf(s[jj] - mnew); psum += p[jj]; }
        psum += __shfl_xor(psum, 1, 64);
        psum += __shfl_xor(psum, 2, 64);
        psum += __shfl_xor(psum, 4, 64);
        l = l * corr + psum;
        m = mnew;

        float4 p0 = {p[0], p[1], p[2], p[3]};
        float4 p1 = {p[4], p[5], p[6], p[7]};
        *(float4*)&Ps[r][sub * 8]     = p0;
        *(float4*)&Ps[r][sub * 8 + 4] = p1;

        #pragma unroll
        for (int dd = 0; dd < 8; ++dd) acc[dd] *= corr;

        __syncthreads();

        #pragma unroll
        for (int j4 = 0; j4 < 64; j4 += 4) {
            float4 p4 = *(const float4*)&Ps[r][j4];
            float pj[4] = {p4.x, p4.y, p4.z, p4.w};
            #pragma unroll
            for (int u = 0; u < 4; ++u) {
                float4 va  = *(const float4*)&Vs[j4 + u][sub * 8];
                float4 vb2 = *(const float4*)&Vs[j4 + u][sub * 8 + 4];
                acc[0] += pj[u]*va.x;  acc[1] += pj[u]*va.y;
                acc[2] += pj[u]*va.z;  acc[3] += pj[u]*va.w;
                acc[4] += pj[u]*vb2.x; acc[5] += pj[u]*vb2.y;
                acc[6] += pj[u]*vb2.z; acc[7] += pj[u]*vb2.w;
            }
        }
    }

    const float inv = 1.0f / l;
    float4 o0 = {acc[0]*inv, acc[1]*inv, acc[2]*inv, acc[3]*inv};
    float4 o1 = {acc[4]*inv, acc[5]*inv, acc[6]*inv, acc[7]*inv};
    float* dst = out + (size_t)b * SEQ * HEAD + (size_t)qrow * HEAD + sub * 8;
    *(float4*)(dst)     = o0;
    *(float4*)(dst + 4) = o1;
}

// ---------------------------------------------------------------------------
extern "C" void kernel_launch(void* const* d_in, const int* in_sizes, int n_in,
                              void* d_out, int out_size, void* d_ws, size_t ws_size,
                              hipStream_t stream) {
    const float* x  = (const float*)d_in[0];
    const float* Wq = (const float*)d_in[1];
    const float* bq = (const float*)d_in[2];
    const float* Wk = (const float*)d_in[3];
    const float* bk = (const float*)d_in[4];
    const float* Wv = (const float*)d_in[5];
    const float* bv = (const float*)d_in[6];

    float* qw = (float*)d_ws;
    float* kw = qw + (size_t)ROWS * HEAD;
    float* vw = kw + (size_t)ROWS * HEAD;
    float* o  = (float*)d_out;

    qkv_proj<<<dim3(ROWS / 32), dim3(256), 0, stream>>>(
        x, Wq, bq, Wk, bk, Wv, bv, qw, kw, vw);

    attn_fwd<<<dim3(SEQ / 32, BATCH), dim3(256), 0, stream>>>(qw, kw, vw, o);
}

// Round 3
// 255.170 us; speedup vs baseline: 4.4056x; 4.4056x over previous
//
#include <hip/hip_runtime.h>
#include <hip/hip_bf16.h>

#define D_MODEL 1024
#define HEAD    64
#define SEQ     2048
#define BATCH   4
#define ROWS    (BATCH * SEQ)   // 8192

typedef __attribute__((ext_vector_type(8))) short  short8;   // 8 bf16 = 4 VGPR
typedef __attribute__((ext_vector_type(4))) float  f32x4;

__device__ __forceinline__ unsigned short f2bf(float f) {
    union { __hip_bfloat16 h; unsigned short u; } c;
    c.h = __float2bfloat16(f);
    return c.u;
}

// ---------------------------------------------------------------------------
// Kernel 0: W -> Wt bf16, transposed+concatenated: Wt[n][k], n in [0,192).
// n/64 selects matrix (q,k,v), n%64 is the output column.
// ---------------------------------------------------------------------------
__global__ __launch_bounds__(256) void conv_w(
    const float* __restrict__ Wq, const float* __restrict__ Wk,
    const float* __restrict__ Wv, unsigned short* __restrict__ Wt)
{
    const int n = blockIdx.x;                 // 0..191
    const float* W = (n < 64) ? Wq : (n < 128 ? Wk : Wv);
    const int col = n & 63;
    for (int k = threadIdx.x; k < D_MODEL; k += 256)
        Wt[(size_t)n * D_MODEL + k] = f2bf(W[(size_t)k * HEAD + col]);
}

// ---------------------------------------------------------------------------
// Kernel 1: MFMA bf16 GEMM  C[8192][192] = x[8192][1024] . W[1024][192] + b
// BM=128 BN=64 BK=64; grid (64,3); 4 waves, wave-tile 64x32 (4x2 16x16 frags).
// A reg-staged with f32->bf16 convert, B reg-staged bf16; T14 split (load
// early / LDS-write after compute); XOR swizzle slot^=(row&7) on both tiles
// so ds_read_b128 fragment reads are 2-way (free).
// q,k,v written f32 for the (unchanged) fp32 attention kernel.
// ---------------------------------------------------------------------------
__global__ __launch_bounds__(256) void gemm_qkv(
    const float* __restrict__ x, const unsigned short* __restrict__ Wt,
    const float* __restrict__ bq, const float* __restrict__ bk,
    const float* __restrict__ bv,
    float* __restrict__ q, float* __restrict__ k, float* __restrict__ v)
{
    __shared__ unsigned short As[2][128 * 64];   // 16 KB each buf
    __shared__ unsigned short Bs[2][64 * 64];    //  8 KB each buf

    const int tid  = threadIdx.x;
    const int lane = tid & 63;
    const int w    = tid >> 6;
    const int wm   = w >> 1;          // 0..1 : rows wm*64..
    const int wn   = w & 1;           // 0..1 : cols wn*32..
    const int row0 = blockIdx.x * 128;
    const int n0   = blockIdx.y * 64;

    const int srow = tid >> 3;        // staging row-within-32-group
    const int slot = tid & 7;         // 16B slot within 128B row

    f32x4 acc[4][2] = {};

    // ---- prologue: stage tile 0 ----
    {
        #pragma unroll
        for (int i = 0; i < 4; ++i) {
            const int row = i * 32 + srow;
            const float* s = x + (size_t)(row0 + row) * D_MODEL + slot * 8;
            f32x4 u0 = *(const f32x4*)s, u1 = *(const f32x4*)(s + 4);
            short8 p;
            p[0]=f2bf(u0[0]); p[1]=f2bf(u0[1]); p[2]=f2bf(u0[2]); p[3]=f2bf(u0[3]);
            p[4]=f2bf(u1[0]); p[5]=f2bf(u1[1]); p[6]=f2bf(u1[2]); p[7]=f2bf(u1[3]);
            *(short8*)&As[0][row * 64 + ((slot ^ (row & 7)) * 8)] = p;
        }
        #pragma unroll
        for (int i = 0; i < 2; ++i) {
            const int n = i * 32 + srow;
            short8 p = *(const short8*)(Wt + (size_t)(n0 + n) * D_MODEL + slot * 8);
            *(short8*)&Bs[0][n * 64 + ((slot ^ (n & 7)) * 8)] = p;
        }
    }
    __syncthreads();

    int buf = 0;
    #pragma unroll 1
    for (int t = 0; t < 16; ++t) {
        const int k0n = (t + 1) * 64;
        f32x4 la[4][2]; short8 lb[2];
        if (t < 15) {
            #pragma unroll
            for (int i = 0; i < 4; ++i) {
                const int row = i * 32 + srow;
                const float* s = x + (size_t)(row0 + row) * D_MODEL + k0n + slot * 8;
                la[i][0] = *(const f32x4*)s;
                la[i][1] = *(const f32x4*)(s + 4);
            }
            #pragma unroll
            for (int i = 0; i < 2; ++i) {
                const int n = i * 32 + srow;
                lb[i] = *(const short8*)(Wt + (size_t)(n0 + n) * D_MODEL + k0n + slot * 8);
            }
        }

        // ---- compute current buffer ----
        #pragma unroll
        for (int ks = 0; ks < 2; ++ks) {
            short8 af[4], bfr[2];
            #pragma unroll
            for (int mi = 0; mi < 4; ++mi) {
                const int row = wm * 64 + mi * 16 + (lane & 15);
                const int sl  = ks * 4 + (lane >> 4);
                af[mi] = *(const short8*)&As[buf][row * 64 + ((sl ^ (row & 7)) * 8)];
            }
            #pragma unroll
            for (int ni = 0; ni < 2; ++ni) {
                const int n  = wn * 32 + ni * 16 + (lane & 15);
                const int sl = ks * 4 + (lane >> 4);
                bfr[ni] = *(const short8*)&Bs[buf][n * 64 + ((sl ^ (n & 7)) * 8)];
            }
            #pragma unroll
            for (int mi = 0; mi < 4; ++mi)
                #pragma unroll
                for (int ni = 0; ni < 2; ++ni)
                    acc[mi][ni] = __builtin_amdgcn_mfma_f32_16x16x32_bf16(
                        af[mi], bfr[ni], acc[mi][ni], 0, 0, 0);
        }

        // ---- late LDS write of next tile ----
        if (t < 15) {
            #pragma unroll
            for (int i = 0; i < 4; ++i) {
                const int row = i * 32 + srow;
                short8 p;
                p[0]=f2bf(la[i][0][0]); p[1]=f2bf(la[i][0][1]);
                p[2]=f2bf(la[i][0][2]); p[3]=f2bf(la[i][0][3]);
                p[4]=f2bf(la[i][1][0]); p[5]=f2bf(la[i][1][1]);
                p[6]=f2bf(la[i][1][2]); p[7]=f2bf(la[i][1][3]);
                *(short8*)&As[buf ^ 1][row * 64 + ((slot ^ (row & 7)) * 8)] = p;
            }
            #pragma unroll
            for (int i = 0; i < 2; ++i) {
                const int n = i * 32 + srow;
                *(short8*)&Bs[buf ^ 1][n * 64 + ((slot ^ (n & 7)) * 8)] = lb[i];
            }
        }
        __syncthreads();
        buf ^= 1;
    }

    // ---- epilogue: bias + f32 store ----
    const float* bias = (blockIdx.y == 0) ? bq : (blockIdx.y == 1 ? bk : bv);
    float* outp       = (blockIdx.y == 0) ? q  : (blockIdx.y == 1 ? k  : v);
    #pragma unroll
    for (int ni = 0; ni < 2; ++ni) {
        const int col = wn * 32 + ni * 16 + (lane & 15);
        const float bcol = bias[col];
        #pragma unroll
        for (int mi = 0; mi < 4; ++mi) {
            #pragma unroll
            for (int r = 0; r < 4; ++r) {
                const int rowg = row0 + wm * 64 + mi * 16 + (lane >> 4) * 4 + r;
                outp[(size_t)rowg * HEAD + col] = acc[mi][ni][r] + bcol;
            }
        }
    }
}

// ---------------------------------------------------------------------------
// Kernel 2: causal flash attention, fp32 vector-ALU (unchanged from R1 pass).
// ---------------------------------------------------------------------------
__device__ __forceinline__ int kswz(int row, int d) {
    return ((((d >> 2) ^ (row >> 3)) & 15) << 2) | (d & 3);
}

__global__ __launch_bounds__(256) void attn_fwd(
    const float* __restrict__ q, const float* __restrict__ k,
    const float* __restrict__ v, float* __restrict__ out)
{
    __shared__ float Qs[32][68];
    __shared__ float Ks[64][64];   // swizzled
    __shared__ float Vs[64][64];
    __shared__ float Ps[32][68];

    const int tid = threadIdx.x;
    const int b   = blockIdx.y;
    const int q0  = blockIdx.x * 32;
    const int r   = tid >> 3;
    const int sub = tid & 7;

    const float* qb = q + (size_t)b * SEQ * HEAD;
    const float* kb = k + (size_t)b * SEQ * HEAD;
    const float* vb = v + (size_t)b * SEQ * HEAD;

    {
        const float* src = qb + (size_t)(q0 + r) * HEAD + sub * 8;
        #pragma unroll
        for (int u = 0; u < 8; ++u) Qs[r][sub * 8 + u] = src[u] * 0.125f;
    }

    float m = -3.0e38f, l = 0.0f;
    float acc[8] = {};

    const int ntiles = ((q0 + 31) >> 6) + 1;
    const int qrow   = q0 + r;

    for (int t = 0; t < ntiles; ++t) {
        const int kv0 = t * 64;

        __syncthreads();
        {
            const int krow = tid >> 3;
            const int c    = (tid & 7) * 8;
            const float* ksrc0 = kb + (size_t)(kv0 + krow)      * HEAD + c;
            const float* ksrc1 = kb + (size_t)(kv0 + krow + 32) * HEAD + c;
            const float* vsrc0 = vb + (size_t)(kv0 + krow)      * HEAD + c;
            const float* vsrc1 = vb + (size_t)(kv0 + krow + 32) * HEAD + c;
            float4 k00 = *(const float4*)(ksrc0);
            float4 k01 = *(const float4*)(ksrc0 + 4);
            float4 k10 = *(const float4*)(ksrc1);
            float4 k11 = *(const float4*)(ksrc1 + 4);
            *(float4*)&Ks[krow][kswz(krow, c)]             = k00;
            *(float4*)&Ks[krow][kswz(krow, c + 4)]         = k01;
            *(float4*)&Ks[krow + 32][kswz(krow + 32, c)]   = k10;
            *(float4*)&Ks[krow + 32][kswz(krow + 32, c+4)] = k11;
            *(float4*)&Vs[krow][c]          = *(const float4*)(vsrc0);
            *(float4*)&Vs[krow][c + 4]      = *(const float4*)(vsrc0 + 4);
            *(float4*)&Vs[krow + 32][c]     = *(const float4*)(vsrc1);
            *(float4*)&Vs[krow + 32][c + 4] = *(const float4*)(vsrc1 + 4);
        }
        __syncthreads();

        float s[8] = {};
        #pragma unroll
        for (int d = 0; d < 64; d += 4) {
            float4 q4 = *(const float4*)&Qs[r][d];
            #pragma unroll
            for (int jj = 0; jj < 8; ++jj) {
                const int row = sub * 8 + jj;
                float4 k4 = *(const float4*)&Ks[row][kswz(row, d)];
                s[jj] += q4.x*k4.x + q4.y*k4.y + q4.z*k4.z + q4.w*k4.w;
            }
        }

        const bool full = (kv0 + 63 <= q0);
        if (!full) {
            #pragma unroll
            for (int jj = 0; jj < 8; ++jj)
                if (kv0 + sub * 8 + jj > qrow) s[jj] = -3.0e38f;
        }

        float tm = s[0];
        #pragma unroll
        for (int jj = 1; jj < 8; ++jj) tm = fmaxf(tm, s[jj]);
        tm = fmaxf(tm, __shfl_xor(tm, 1, 64));
        tm = fmaxf(tm, __shfl_xor(tm, 2, 64));
        tm = fmaxf(tm, __shfl_xor(tm, 4, 64));

        const float mnew = fmaxf(m, tm);
        const float corr = __expf(m - mnew);
        float p[8], psum = 0.0f;
        #pragma unroll
        for (int jj = 0; jj < 8; ++jj) { p[jj] = __expf(s[jj] - mnew); psum += p[jj]; }
        psum += __shfl_xor(psum, 1, 64);
        psum += __shfl_xor(psum, 2, 64);
        psum += __shfl_xor(psum, 4, 64);
        l = l * corr + psum;
        m = mnew;

        float4 p0 = {p[0], p[1], p[2], p[3]};
        float4 p1 = {p[4], p[5], p[6], p[7]};
        *(float4*)&Ps[r][sub * 8]     = p0;
        *(float4*)&Ps[r][sub * 8 + 4] = p1;

        #pragma unroll
        for (int dd = 0; dd < 8; ++dd) acc[dd] *= corr;

        __syncthreads();

        #pragma unroll
        for (int j4 = 0; j4 < 64; j4 += 4) {
            float4 p4 = *(const float4*)&Ps[r][j4];
            float pj[4] = {p4.x, p4.y, p4.z, p4.w};
            #pragma unroll
            for (int u = 0; u < 4; ++u) {
                float4 va  = *(const float4*)&Vs[j4 + u][sub * 8];
                float4 vb2 = *(const float4*)&Vs[j4 + u][sub * 8 + 4];
                acc[0] += pj[u]*va.x;  acc[1] += pj[u]*va.y;
                acc[2] += pj[u]*va.z;  acc[3] += pj[u]*va.w;
                acc[4] += pj[u]*vb2.x; acc[5] += pj[u]*vb2.y;
                acc[6] += pj[u]*vb2.z; acc[7] += pj[u]*vb2.w;
            }
        }
    }

    const float inv = 1.0f / l;
    float4 o0 = {acc[0]*inv, acc[1]*inv, acc[2]*inv, acc[3]*inv};
    float4 o1 = {acc[4]*inv, acc[5]*inv, acc[6]*inv, acc[7]*inv};
    float* dst = out + (size_t)b * SEQ * HEAD + (size_t)qrow * HEAD + sub * 8;
    *(float4*)(dst)     = o0;
    *(float4*)(dst + 4) = o1;
}

// ---------------------------------------------------------------------------
extern "C" void kernel_launch(void* const* d_in, const int* in_sizes, int n_in,
                              void* d_out, int out_size, void* d_ws, size_t ws_size,
                              hipStream_t stream) {
    const float* x  = (const float*)d_in[0];
    const float* Wq = (const float*)d_in[1];
    const float* bq = (const float*)d_in[2];
    const float* Wk = (const float*)d_in[3];
    const float* bk = (const float*)d_in[4];
    const float* Wv = (const float*)d_in[5];
    const float* bv = (const float*)d_in[6];

    unsigned short* Wt = (unsigned short*)d_ws;                 // 384 KB
    float* qw = (float*)((char*)d_ws + (size_t)192 * D_MODEL * 2);
    float* kw = qw + (size_t)ROWS * HEAD;
    float* vw = kw + (size_t)ROWS * HEAD;
    float* o  = (float*)d_out;

    conv_w<<<dim3(192), dim3(256), 0, stream>>>(Wq, Wk, Wv, Wt);
    gemm_qkv<<<dim3(64, 3), dim3(256), 0, stream>>>(x, Wt, bq, bk, bv, qw, kw, vw);
    attn_fwd<<<dim3(SEQ / 32, BATCH), dim3(256), 0, stream>>>(qw, kw, vw, o);
}

// Round 4
// 158.794 us; speedup vs baseline: 7.0795x; 1.6069x over previous
//
#include <hip/hip_runtime.h>
#include <hip/hip_bf16.h>

#define D_MODEL 1024
#define HEAD    64
#define SEQ     2048
#define BATCH   4
#define ROWS    (BATCH * SEQ)   // 8192

typedef __attribute__((ext_vector_type(8))) short  short8;   // 8 bf16 = 4 VGPR
typedef __attribute__((ext_vector_type(4))) short  short4v;  // 4 bf16 = 2 VGPR
typedef __attribute__((ext_vector_type(4))) float  f32x4;

__device__ __forceinline__ unsigned short f2bf(float f) {
    union { __hip_bfloat16 h; unsigned short u; } c;
    c.h = __float2bfloat16(f);
    return c.u;
}

// ---------------------------------------------------------------------------
// Kernel 0: W -> Wt bf16, transposed+concatenated: Wt[n][k], n in [0,192).
// ---------------------------------------------------------------------------
__global__ __launch_bounds__(256) void conv_w(
    const float* __restrict__ Wq, const float* __restrict__ Wk,
    const float* __restrict__ Wv, unsigned short* __restrict__ Wt)
{
    const int n = blockIdx.x;                 // 0..191
    const float* W = (n < 64) ? Wq : (n < 128 ? Wk : Wv);
    const int col = n & 63;
    for (int k = threadIdx.x; k < D_MODEL; k += 256)
        Wt[(size_t)n * D_MODEL + k] = f2bf(W[(size_t)k * HEAD + col]);
}

// ---------------------------------------------------------------------------
// Kernel 1: MFMA bf16 GEMM  C[8192][192] = x . W + b, x read ONCE from HBM.
// BM=32 BN=192 BK=32; grid 256; 2 waves; wave-tile 16x192 (12 n-frags).
// Outputs: qb bf16 (x0.125, +bq), kb bf16 (+bk), vw f32 (+bv).
// ---------------------------------------------------------------------------
__global__ __launch_bounds__(128) void gemm_qkv(
    const float* __restrict__ x, const unsigned short* __restrict__ Wt,
    const float* __restrict__ bq, const float* __restrict__ bk,
    const float* __restrict__ bv,
    unsigned short* __restrict__ qb, unsigned short* __restrict__ kb,
    float* __restrict__ vw)
{
    __shared__ unsigned short As[2][32 * 32];    // 2 KB each
    __shared__ unsigned short Bs[2][192 * 32];   // 12 KB each

    const int tid  = threadIdx.x;
    const int lane = tid & 63;
    const int w    = tid >> 6;        // wave 0/1 -> q-rows w*16..
    const int l15  = lane & 15;
    const int g    = lane >> 4;       // 0..3
    const int row0 = blockIdx.x * 32;

    const int arow  = tid >> 2;       // 0..31
    const int aslot = tid & 3;        // 0..3

    f32x4 acc[12] = {};

    // ---- prologue: stage tile 0 ----
    {
        const float* s = x + (size_t)(row0 + arow) * D_MODEL + aslot * 8;
        f32x4 u0 = *(const f32x4*)s, u1 = *(const f32x4*)(s + 4);
        short8 p;
        p[0]=f2bf(u0[0]); p[1]=f2bf(u0[1]); p[2]=f2bf(u0[2]); p[3]=f2bf(u0[3]);
        p[4]=f2bf(u1[0]); p[5]=f2bf(u1[1]); p[6]=f2bf(u1[2]); p[7]=f2bf(u1[3]);
        *(short8*)&As[0][arow * 32 + ((aslot ^ (arow & 3)) * 8)] = p;
        #pragma unroll
        for (int u = 0; u < 6; ++u) {
            const int idx = u * 128 + tid;
            const int br = idx >> 2, bs = idx & 3;
            short8 q8 = *(const short8*)(Wt + (size_t)br * D_MODEL + bs * 8);
            *(short8*)&Bs[0][br * 32 + ((bs ^ (br & 3)) * 8)] = q8;
        }
    }
    __syncthreads();

    int cur = 0;
    #pragma unroll 1
    for (int t = 0; t < 32; ++t) {
        f32x4 xa0, xa1; short8 brv[6];
        if (t < 31) {
            const int k0n = (t + 1) * 32;
            const float* s = x + (size_t)(row0 + arow) * D_MODEL + k0n + aslot * 8;
            xa0 = *(const f32x4*)s; xa1 = *(const f32x4*)(s + 4);
            #pragma unroll
            for (int u = 0; u < 6; ++u) {
                const int idx = u * 128 + tid;
                const int br = idx >> 2, bs = idx & 3;
                brv[u] = *(const short8*)(Wt + (size_t)br * D_MODEL + k0n + bs * 8);
            }
        }

        // ---- compute ----
        short8 af = *(const short8*)&As[cur][(w * 16 + l15) * 32 + ((g ^ (l15 & 3)) * 8)];
        #pragma unroll
        for (int ni = 0; ni < 12; ++ni) {
            short8 bf = *(const short8*)&Bs[cur][(ni * 16 + l15) * 32 + ((g ^ (l15 & 3)) * 8)];
            acc[ni] = __builtin_amdgcn_mfma_f32_16x16x32_bf16(af, bf, acc[ni], 0, 0, 0);
        }

        if (t < 31) {
            short8 p;
            p[0]=f2bf(xa0[0]); p[1]=f2bf(xa0[1]); p[2]=f2bf(xa0[2]); p[3]=f2bf(xa0[3]);
            p[4]=f2bf(xa1[0]); p[5]=f2bf(xa1[1]); p[6]=f2bf(xa1[2]); p[7]=f2bf(xa1[3]);
            *(short8*)&As[cur ^ 1][arow * 32 + ((aslot ^ (arow & 3)) * 8)] = p;
            #pragma unroll
            for (int u = 0; u < 6; ++u) {
                const int idx = u * 128 + tid;
                const int br = idx >> 2, bs = idx & 3;
                *(short8*)&Bs[cur ^ 1][br * 32 + ((bs ^ (br & 3)) * 8)] = brv[u];
            }
            __syncthreads();
        }
        cur ^= 1;
    }

    // ---- epilogue ----
    #pragma unroll
    for (int ni = 0; ni < 12; ++ni) {
        const int mat = ni >> 2;                     // 0:q 1:k 2:v
        const int col = (ni & 3) * 16 + l15;
        const float bias = (mat == 0 ? bq : (mat == 1 ? bk : bv))[col];
        #pragma unroll
        for (int r = 0; r < 4; ++r) {
            const int rowg = row0 + w * 16 + g * 4 + r;
            const float val = acc[ni][r] + bias;
            if (mat == 0)      qb[(size_t)rowg * HEAD + col] = f2bf(val * 0.125f);
            else if (mat == 1) kb[(size_t)rowg * HEAD + col] = f2bf(val);
            else               vw[(size_t)rowg * HEAD + col] = val;
        }
    }
}

// ---------------------------------------------------------------------------
// Kernel 2: transpose V once: vw f32 [8192][64] -> vt bf16 [4][64][2048].
// ---------------------------------------------------------------------------
__global__ __launch_bounds__(256) void xpose_v(
    const float* __restrict__ vw, unsigned short* __restrict__ vt)
{
    __shared__ float Ls[64][65];
    const int tid = threadIdx.x;
    const int gr0 = blockIdx.x * 64;          // global row base
    const int b   = gr0 >> 11;
    const int kvb = gr0 & 2047;

    const int row = tid >> 2, c16 = (tid & 3) * 16;
    #pragma unroll
    for (int j = 0; j < 4; ++j) {
        f32x4 v4 = *(const f32x4*)(vw + (size_t)(gr0 + row) * HEAD + c16 + j * 4);
        Ls[row][c16 + j*4 + 0] = v4[0]; Ls[row][c16 + j*4 + 1] = v4[1];
        Ls[row][c16 + j*4 + 2] = v4[2]; Ls[row][c16 + j*4 + 3] = v4[3];
    }
    __syncthreads();

    const int d = tid >> 2, ks = (tid & 3) * 16;
    short8 o0, o1;
    #pragma unroll
    for (int j = 0; j < 8; ++j) o0[j] = f2bf(Ls[ks + j][d]);
    #pragma unroll
    for (int j = 0; j < 8; ++j) o1[j] = f2bf(Ls[ks + 8 + j][d]);
    unsigned short* dst = vt + ((size_t)b * HEAD + d) * SEQ + kvb + ks;
    *(short8*)(dst)     = o0;
    *(short8*)(dst + 8) = o1;
}

// ---------------------------------------------------------------------------
// Kernel 3: causal flash attention, bf16 MFMA.
// QB=32 KB=32; 2 waves (wave w: q-rows w*16..+15); grid (64, 4).
// Swapped QK^T: S^T = mfma(K,Q) -> lane holds 8 kv for one q-col.
// P^T packed to per-wave LDS (pad-40 rows), read back as PV A-frag.
// V consumed as V^T (vt) so PV B-frags are row reads.
// ---------------------------------------------------------------------------
__global__ __launch_bounds__(128) void attn_fwd(
    const unsigned short* __restrict__ qb, const unsigned short* __restrict__ kb,
    const unsigned short* __restrict__ vt, float* __restrict__ out)
{
    __shared__ unsigned short Qs[32 * 64];        // swz slot^(row&7)
    __shared__ unsigned short Ks[2][32 * 64];     // swz slot^(row&7)
    __shared__ unsigned short Vs[2][64 * 32];     // V^T tile, swz slot^(d&3)
    __shared__ unsigned short Ps[2][16 * 40];     // per-wave P, pad-40

    const int tid  = threadIdx.x;
    const int lane = tid & 63;
    const int w    = tid >> 6;
    const int l15  = lane & 15;
    const int g    = lane >> 4;        // 0..3
    const int b    = blockIdx.y;
    const int qt   = blockIdx.x;
    const int q0   = qt * 32;

    const unsigned short* qg = qb + (size_t)(b * SEQ) * HEAD;
    const unsigned short* kg = kb + (size_t)(b * SEQ) * HEAD;
    const unsigned short* vg = vt + (size_t)b * HEAD * SEQ;

    // ---- stage Q (once) + K/V tile 0 ----
    #pragma unroll
    for (int u = 0; u < 2; ++u) {
        const int idx = u * 128 + tid;
        const int row = idx >> 3, slot = idx & 7;
        *(short8*)&Qs[row * 64 + ((slot ^ (row & 7)) * 8)] =
            *(const short8*)(qg + (size_t)(q0 + row) * HEAD + slot * 8);
        *(short8*)&Ks[0][row * 64 + ((slot ^ (row & 7)) * 8)] =
            *(const short8*)(kg + (size_t)row * HEAD + slot * 8);
        const int d = idx >> 2, vslot = idx & 3;
        *(short8*)&Vs[0][d * 32 + ((vslot ^ (d & 3)) * 8)] =
            *(const short8*)(vg + (size_t)d * SEQ + vslot * 8);
    }
    __syncthreads();

    float m = -1.0e30f, l = 0.0f;
    f32x4 acc_o[4] = {};
    const int nt = qt + 1;
    int cur = 0;

    const int qloc = w * 16 + l15;     // this lane's q (stats owner)

    #pragma unroll 1
    for (int t = 0; t < nt; ++t) {
        // ---- prefetch next tile into regs ----
        short8 kr[2], vr[2];
        if (t + 1 < nt) {
            const int kv0n = (t + 1) * 32;
            #pragma unroll
            for (int u = 0; u < 2; ++u) {
                const int idx = u * 128 + tid;
                const int row = idx >> 3, slot = idx & 7;
                kr[u] = *(const short8*)(kg + (size_t)(kv0n + row) * HEAD + slot * 8);
                const int d = idx >> 2, vslot = idx & 3;
                vr[u] = *(const short8*)(vg + (size_t)d * SEQ + kv0n + vslot * 8);
            }
        }

        // ---- QK^T (swapped): S^T[kv][q] ----
        f32x4 sA[2] = {};
        #pragma unroll
        for (int ks = 0; ks < 2; ++ks) {
            short8 qf = *(const short8*)&Qs[(w * 16 + l15) * 64 + (((ks * 4 + g) ^ (l15 & 7)) * 8)];
            #pragma unroll
            for (int mf = 0; mf < 2; ++mf) {
                const int krow = mf * 16 + l15;
                short8 kf = *(const short8*)&Ks[cur][krow * 64 + (((ks * 4 + g) ^ (krow & 7)) * 8)];
                sA[mf] = __builtin_amdgcn_mfma_f32_16x16x32_bf16(kf, qf, sA[mf], 0, 0, 0);
            }
        }

        // ---- causal mask (last tile only: kv0 == q0) ----
        if (t == nt - 1) {
            #pragma unroll
            for (int mf = 0; mf < 2; ++mf)
                #pragma unroll
                for (int r = 0; r < 4; ++r)
                    if (mf * 16 + g * 4 + r > qloc) sA[mf][r] = -1.0e30f;
        }

        // ---- online softmax (per q = l15, spread over 4 lane-copies) ----
        float smax = sA[0][0];
        #pragma unroll
        for (int r = 1; r < 4; ++r) smax = fmaxf(smax, sA[0][r]);
        #pragma unroll
        for (int r = 0; r < 4; ++r) smax = fmaxf(smax, sA[1][r]);
        smax = fmaxf(smax, __shfl_xor(smax, 16, 64));
        smax = fmaxf(smax, __shfl_xor(smax, 32, 64));

        const float mnew = fmaxf(m, smax);
        const float corr = __expf(m - mnew);
        float p[8], psum = 0.0f;
        #pragma unroll
        for (int mf = 0; mf < 2; ++mf)
            #pragma unroll
            for (int r = 0; r < 4; ++r) {
                p[mf * 4 + r] = __expf(sA[mf][r] - mnew);
                psum += p[mf * 4 + r];
            }
        psum += __shfl_xor(psum, 16, 64);
        psum += __shfl_xor(psum, 32, 64);
        l = l * corr + psum;
        m = mnew;

        // ---- pack P^T -> Ps[q][kv] (b64, kv-contiguous per lane) ----
        #pragma unroll
        for (int mf = 0; mf < 2; ++mf) {
            short4v pk;
            pk[0] = f2bf(p[mf*4+0]); pk[1] = f2bf(p[mf*4+1]);
            pk[2] = f2bf(p[mf*4+2]); pk[3] = f2bf(p[mf*4+3]);
            *(short4v*)&Ps[w][l15 * 40 + mf * 16 + g * 4] = pk;
        }

        // ---- rescale O by corr (per-row q via bpermute) ----
        float cf[4];
        #pragma unroll
        for (int r = 0; r < 4; ++r) cf[r] = __shfl(corr, w * 16 + g * 4 + r, 64);
        #pragma unroll
        for (int ni = 0; ni < 4; ++ni)
            #pragma unroll
            for (int r = 0; r < 4; ++r) acc_o[ni][r] *= cf[r];

        // ---- PV: O[q][d] += P[q][kv] . V^T[d][kv] ----
        short8 pf = *(const short8*)&Ps[w][l15 * 40 + g * 8];
        #pragma unroll
        for (int ni = 0; ni < 4; ++ni) {
            const int d = ni * 16 + l15;
            short8 vf = *(const short8*)&Vs[cur][d * 32 + ((g ^ (d & 3)) * 8)];
            acc_o[ni] = __builtin_amdgcn_mfma_f32_16x16x32_bf16(pf, vf, acc_o[ni], 0, 0, 0);
        }

        // ---- publish next tile ----
        if (t + 1 < nt) {
            #pragma unroll
            for (int u = 0; u < 2; ++u) {
                const int idx = u * 128 + tid;
                const int row = idx >> 3, slot = idx & 7;
                *(short8*)&Ks[cur ^ 1][row * 64 + ((slot ^ (row & 7)) * 8)] = kr[u];
                const int d = idx >> 2, vslot = idx & 3;
                *(short8*)&Vs[cur ^ 1][d * 32 + ((vslot ^ (d & 3)) * 8)] = vr[u];
            }
            __syncthreads();
        }
        cur ^= 1;
    }

    // ---- epilogue: divide by l, store f32 ----
    float lf[4];
    #pragma unroll
    for (int r = 0; r < 4; ++r) lf[r] = __shfl(l, w * 16 + g * 4 + r, 64);
    #pragma unroll
    for (int ni = 0; ni < 4; ++ni) {
        #pragma unroll
        for (int r = 0; r < 4; ++r) {
            const int rowg = q0 + w * 16 + g * 4 + r;
            out[((size_t)b * SEQ + rowg) * HEAD + ni * 16 + l15] = acc_o[ni][r] / lf[r];
        }
    }
}

// ---------------------------------------------------------------------------
extern "C" void kernel_launch(void* const* d_in, const int* in_sizes, int n_in,
                              void* d_out, int out_size, void* d_ws, size_t ws_size,
                              hipStream_t stream) {
    const float* x  = (const float*)d_in[0];
    const float* Wq = (const float*)d_in[1];
    const float* bq = (const float*)d_in[2];
    const float* Wk = (const float*)d_in[3];
    const float* bk = (const float*)d_in[4];
    const float* Wv = (const float*)d_in[5];
    const float* bv = (const float*)d_in[6];

    unsigned short* Wt = (unsigned short*)d_ws;                 // 192*1024*2B
    unsigned short* qbp = Wt + (size_t)192 * D_MODEL;           // 1 MB
    unsigned short* kbp = qbp + (size_t)ROWS * HEAD;            // 1 MB
    float*          vw  = (float*)(kbp + (size_t)ROWS * HEAD);  // 2 MB
    unsigned short* vtp = (unsigned short*)(vw + (size_t)ROWS * HEAD); // 1 MB
    float* o = (float*)d_out;

    conv_w  <<<dim3(192),    dim3(256), 0, stream>>>(Wq, Wk, Wv, Wt);
    gemm_qkv<<<dim3(256),    dim3(128), 0, stream>>>(x, Wt, bq, bk, bv, qbp, kbp, vw);
    xpose_v <<<dim3(128),    dim3(256), 0, stream>>>(vw, vtp);
    attn_fwd<<<dim3(64, 4),  dim3(128), 0, stream>>>(qbp, kbp, vtp, o);
}

// Round 5
// 121.383 us; speedup vs baseline: 9.2614x; 1.3082x over previous
//
#include <hip/hip_runtime.h>
#include <hip/hip_bf16.h>

#define D_MODEL 1024
#define HEAD    64
#define SEQ     2048
#define BATCH   4
#define ROWS    (BATCH * SEQ)   // 8192

typedef __attribute__((ext_vector_type(8))) short  short8;   // 8 bf16
typedef __attribute__((ext_vector_type(4))) short  short4v;  // 4 bf16
typedef __attribute__((ext_vector_type(4))) float  f32x4;

__device__ __forceinline__ unsigned short f2bf(float f) {
    union { __hip_bfloat16 h; unsigned short u; } c;
    c.h = __float2bfloat16(f);
    return c.u;
}

// ---------------------------------------------------------------------------
// Kernel 0: W[1024][64] f32 -> Wt[192][1024] bf16 (transposed, q|k|v concat).
// 48 blocks: mat = bx>>4, k0 = (bx&15)*64. LDS transpose, coalesced both sides.
// ---------------------------------------------------------------------------
__global__ __launch_bounds__(256) void conv_w(
    const float* __restrict__ Wq, const float* __restrict__ Wk,
    const float* __restrict__ Wv, unsigned short* __restrict__ Wt)
{
    __shared__ float Lw[64][65];
    const int tid = threadIdx.x;
    const int mat = blockIdx.x >> 4;
    const int k0  = (blockIdx.x & 15) * 64;
    const float* W = (mat == 0) ? Wq : (mat == 1 ? Wk : Wv);

    // read 64x64 f32 tile coalesced (f32x4 per thread x4)
    #pragma unroll
    for (int j = 0; j < 4; ++j) {
        const int idx = j * 1024 + tid * 4;       // element in tile
        const int r = idx >> 6, c = idx & 63;
        f32x4 v4 = *(const f32x4*)(W + (size_t)(k0 + r) * HEAD + c);
        Lw[r][c] = v4[0]; Lw[r][c+1] = v4[1]; Lw[r][c+2] = v4[2]; Lw[r][c+3] = v4[3];
    }
    __syncthreads();

    const int col = tid >> 2, kc = (tid & 3) * 16;
    short8 o0, o1;
    #pragma unroll
    for (int j = 0; j < 8; ++j) o0[j] = f2bf(Lw[kc + j][col]);
    #pragma unroll
    for (int j = 0; j < 8; ++j) o1[j] = f2bf(Lw[kc + 8 + j][col]);
    unsigned short* dst = Wt + (size_t)(mat * 64 + col) * D_MODEL + k0 + kc;
    *(short8*)(dst)     = o0;
    *(short8*)(dst + 8) = o1;
}

// ---------------------------------------------------------------------------
// Kernel 1: MFMA bf16 GEMM  C[8192][192] = x . Wt^T + b.
// BM=32 BN=192 BK=64; grid 256; 4 waves (2m x 2n), per-wave 16 rows x 96 cols.
// Epilogue: qb = bf16((c+bq)*0.125), kb = bf16(c+bk), v -> V^T bf16 via LDS.
// Pad-68 LDS rows: frag reads 2-way-free, staging writes min-cycle.
// ---------------------------------------------------------------------------
__global__ __launch_bounds__(256) void gemm_qkv(
    const float* __restrict__ x, const unsigned short* __restrict__ Wt,
    const float* __restrict__ bq, const float* __restrict__ bk,
    const float* __restrict__ bv,
    unsigned short* __restrict__ qb, unsigned short* __restrict__ kb,
    unsigned short* __restrict__ vt)
{
    __shared__ unsigned short As[2][32 * 68];    // 4.25 KB each
    __shared__ unsigned short Bs[2][192 * 68];   // 25.5 KB each
    __shared__ float Vx[32][66];                 // 8.25 KB (v-transpose buffer)

    const int tid  = threadIdx.x;
    const int lane = tid & 63;
    const int w    = tid >> 6;
    const int wm   = w >> 1, wn = w & 1;
    const int l15  = lane & 15;
    const int g    = lane >> 4;
    const int row0 = blockIdx.x * 32;

    const int arow = tid >> 3, aslot = tid & 7;

    f32x4 acc[6] = {};

    // ---- prologue: stage tile 0 ----
    {
        const float* s = x + (size_t)(row0 + arow) * D_MODEL + aslot * 8;
        f32x4 u0 = *(const f32x4*)s, u1 = *(const f32x4*)(s + 4);
        short8 p;
        p[0]=f2bf(u0[0]); p[1]=f2bf(u0[1]); p[2]=f2bf(u0[2]); p[3]=f2bf(u0[3]);
        p[4]=f2bf(u1[0]); p[5]=f2bf(u1[1]); p[6]=f2bf(u1[2]); p[7]=f2bf(u1[3]);
        *(short8*)&As[0][arow * 68 + aslot * 8] = p;
        #pragma unroll
        for (int u = 0; u < 6; ++u) {
            const int idx = u * 256 + tid;
            const int bn = idx >> 3, bslot = idx & 7;
            *(short8*)&Bs[0][bn * 68 + bslot * 8] =
                *(const short8*)(Wt + (size_t)bn * D_MODEL + bslot * 8);
        }
    }
    __syncthreads();

    int cur = 0;
    #pragma unroll 1
    for (int t = 0; t < 16; ++t) {
        f32x4 xa0, xa1; short8 brv[6];
        if (t < 15) {
            const int k0 = (t + 1) * 64;
            const float* s = x + (size_t)(row0 + arow) * D_MODEL + k0 + aslot * 8;
            xa0 = *(const f32x4*)s; xa1 = *(const f32x4*)(s + 4);
            #pragma unroll
            for (int u = 0; u < 6; ++u) {
                const int idx = u * 256 + tid;
                const int bn = idx >> 3, bslot = idx & 7;
                brv[u] = *(const short8*)(Wt + (size_t)bn * D_MODEL + k0 + bslot * 8);
            }
        }

        #pragma unroll
        for (int ks = 0; ks < 2; ++ks) {
            short8 af = *(const short8*)&As[cur][(wm * 16 + l15) * 68 + ks * 32 + g * 8];
            #pragma unroll
            for (int ni = 0; ni < 6; ++ni) {
                short8 bf = *(const short8*)&Bs[cur][(wn * 96 + ni * 16 + l15) * 68 + ks * 32 + g * 8];
                acc[ni] = __builtin_amdgcn_mfma_f32_16x16x32_bf16(af, bf, acc[ni], 0, 0, 0);
            }
        }

        if (t < 15) {
            short8 p;
            p[0]=f2bf(xa0[0]); p[1]=f2bf(xa0[1]); p[2]=f2bf(xa0[2]); p[3]=f2bf(xa0[3]);
            p[4]=f2bf(xa1[0]); p[5]=f2bf(xa1[1]); p[6]=f2bf(xa1[2]); p[7]=f2bf(xa1[3]);
            *(short8*)&As[cur ^ 1][arow * 68 + aslot * 8] = p;
            #pragma unroll
            for (int u = 0; u < 6; ++u) {
                const int idx = u * 256 + tid;
                const int bn = idx >> 3, bslot = idx & 7;
                *(short8*)&Bs[cur ^ 1][bn * 68 + bslot * 8] = brv[u];
            }
            __syncthreads();
        }
        cur ^= 1;
    }

    // ---- epilogue ----
    #pragma unroll
    for (int ni = 0; ni < 6; ++ni) {
        const int col = wn * 96 + ni * 16 + l15;
        const int mat = col >> 6, mc = col & 63;
        const float bias = (mat == 0 ? bq : (mat == 1 ? bk : bv))[mc];
        #pragma unroll
        for (int r = 0; r < 4; ++r) {
            const int rl = wm * 16 + g * 4 + r;          // row in block
            const float val = acc[ni][r] + bias;
            if (mat == 0)      qb[(size_t)(row0 + rl) * HEAD + mc] = f2bf(val * 0.125f);
            else if (mat == 1) kb[(size_t)(row0 + rl) * HEAD + mc] = f2bf(val);
            else               Vx[rl][mc] = val;
        }
    }
    __syncthreads();

    // transposed V store: vt[b][d][kv], coalesced 64B chunks
    {
        const int mcol = tid >> 2, kvc = (tid & 3) * 8;
        short8 o;
        #pragma unroll
        for (int j = 0; j < 8; ++j) o[j] = f2bf(Vx[kvc + j][mcol]);
        const int bb = row0 >> 11, kvloc = row0 & 2047;
        *(short8*)(vt + ((size_t)bb * HEAD + mcol) * SEQ + kvloc + kvc) = o;
    }
}

// ---------------------------------------------------------------------------
// Kernel 2: causal flash attention, bf16 MFMA, intra-block KV-split.
// Grid (64,4) x 256 thr (4 waves). Block p handles q-tiles {p, 127-p} (QB=16)
// -> balanced ~17 iterations of 128 kv each. Per iteration each wave owns a
// 32-kv slice with INDEPENDENT (m,l,acc) -> one barrier/iter; flash-decoding
// merge per tile at the end via LDS.
// ---------------------------------------------------------------------------
__global__ __launch_bounds__(256) void attn_fwd(
    const unsigned short* __restrict__ qb, const unsigned short* __restrict__ kb,
    const unsigned short* __restrict__ vt, float* __restrict__ out)
{
    __shared__ unsigned short Ks[2][128 * 68];   // 17 KB each
    __shared__ unsigned short Vs[2][64 * 132];   // 16.5 KB each (V^T tile)
    __shared__ unsigned short Qs[16 * 68];       // 2.1 KB
    __shared__ unsigned short Ps[4][16 * 40];    // 1.25 KB / wave
    __shared__ float Cs[4][16 * 68];             // 17 KB (merge buffer)
    __shared__ float Sm[64], Sl[64];

    const int tid  = threadIdx.x;
    const int lane = tid & 63;
    const int w    = tid >> 6;
    const int l15  = lane & 15;
    const int g    = lane >> 4;
    const int b    = blockIdx.y;
    const int p    = blockIdx.x;

    const unsigned short* qg = qb + (size_t)b * SEQ * HEAD;
    const unsigned short* kg = kb + (size_t)b * SEQ * HEAD;
    const unsigned short* vg = vt + (size_t)b * HEAD * SEQ;

    // staging coords
    const int kvrow = tid >> 1, khalf = tid & 1;      // K: 2 thr / 128B row
    const int vd = tid >> 2, vc = tid & 3;            // V: 4 thr / d-row

    #pragma unroll 1
    for (int half = 0; half < 2; ++half) {
        const int j    = half ? (127 - p) : p;
        const int q0   = j * 16;
        const int nkv  = q0 + 16;
        const int iters = (nkv + 127) >> 7;

        // ---- stage Q tile + K/V iteration 0 ----
        if (tid < 128) {
            const int row = tid >> 3, slot = tid & 7;
            *(short8*)&Qs[row * 68 + slot * 8] =
                *(const short8*)(qg + (size_t)(q0 + row) * HEAD + slot * 8);
        }
        #pragma unroll
        for (int u = 0; u < 4; ++u) {
            const int slot = khalf * 4 + u;
            *(short8*)&Ks[0][kvrow * 68 + slot * 8] =
                *(const short8*)(kg + (size_t)kvrow * HEAD + slot * 8);
            const int kv = vc * 8 + 32 * u;
            *(short8*)&Vs[0][vd * 132 + kv] =
                *(const short8*)(vg + (size_t)vd * SEQ + kv);
        }
        __syncthreads();

        // hoist Q fragments (reused every iteration)
        short8 qf0 = *(const short8*)&Qs[l15 * 68 + g * 8];
        short8 qf1 = *(const short8*)&Qs[l15 * 68 + 32 + g * 8];

        float m_w = -1.0e30f, l_w = 0.0f;
        f32x4 acc[4] = {};
        int cur = 0;

        #pragma unroll 1
        for (int it = 0; it < iters; ++it) {
            // ---- prefetch next K/V into regs ----
            short8 kr[4], vr[4];
            if (it + 1 < iters) {
                const int kv0n = (it + 1) * 128;
                #pragma unroll
                for (int u = 0; u < 4; ++u) {
                    const int slot = khalf * 4 + u;
                    kr[u] = *(const short8*)(kg + (size_t)(kv0n + kvrow) * HEAD + slot * 8);
                    const int kv = vc * 8 + 32 * u;
                    vr[u] = *(const short8*)(vg + (size_t)vd * SEQ + kv0n + kv);
                }
            }

            // ---- QK^T (swapped): S^T[kv 32][q 16] for this wave's slice ----
            f32x4 sA[2] = {};
            #pragma unroll
            for (int f = 0; f < 2; ++f) {
                const int row = w * 32 + f * 16 + l15;
                short8 kf0 = *(const short8*)&Ks[cur][row * 68 + g * 8];
                short8 kf1 = *(const short8*)&Ks[cur][row * 68 + 32 + g * 8];
                sA[f] = __builtin_amdgcn_mfma_f32_16x16x32_bf16(kf0, qf0, sA[f], 0, 0, 0);
                sA[f] = __builtin_amdgcn_mfma_f32_16x16x32_bf16(kf1, qf1, sA[f], 0, 0, 0);
            }

            // ---- causal mask (only last iteration can cross the diagonal) ----
            if (it == iters - 1) {
                const int kvb = it * 128 + w * 32 + g * 4;
                const int qg_ = q0 + l15;
                #pragma unroll
                for (int f = 0; f < 2; ++f)
                    #pragma unroll
                    for (int r = 0; r < 4; ++r)
                        if (kvb + f * 16 + r > qg_) sA[f][r] = -1.0e30f;
            }

            // ---- per-wave online softmax (q = l15, copies over g) ----
            float smax = sA[0][0];
            #pragma unroll
            for (int r = 1; r < 4; ++r) smax = fmaxf(smax, sA[0][r]);
            #pragma unroll
            for (int r = 0; r < 4; ++r) smax = fmaxf(smax, sA[1][r]);
            smax = fmaxf(smax, __shfl_xor(smax, 16));
            smax = fmaxf(smax, __shfl_xor(smax, 32));

            const float mnew = fmaxf(m_w, smax);
            const float corr = __expf(m_w - mnew);
            float pv[8], psum = 0.0f;
            #pragma unroll
            for (int f = 0; f < 2; ++f)
                #pragma unroll
                for (int r = 0; r < 4; ++r) {
                    pv[f * 4 + r] = __expf(sA[f][r] - mnew);
                    psum += pv[f * 4 + r];
                }
            psum += __shfl_xor(psum, 16);
            psum += __shfl_xor(psum, 32);
            l_w = l_w * corr + psum;
            m_w = mnew;

            // ---- pack P (per-wave buffer, same-wave read: no barrier) ----
            #pragma unroll
            for (int f = 0; f < 2; ++f) {
                short4v pk;
                pk[0] = f2bf(pv[f*4+0]); pk[1] = f2bf(pv[f*4+1]);
                pk[2] = f2bf(pv[f*4+2]); pk[3] = f2bf(pv[f*4+3]);
                *(short4v*)&Ps[w][l15 * 40 + f * 16 + g * 4] = pk;
            }

            // ---- rescale acc by corr (per q-row) ----
            float cf[4];
            #pragma unroll
            for (int r = 0; r < 4; ++r) cf[r] = __shfl(corr, g * 4 + r);
            #pragma unroll
            for (int ni = 0; ni < 4; ++ni)
                #pragma unroll
                for (int r = 0; r < 4; ++r) acc[ni][r] *= cf[r];

            // ---- PV: O[q][d] += P[q][kv] . V^T[d][kv] (wave's 32-kv slice) ----
            short8 pf = *(const short8*)&Ps[w][l15 * 40 + g * 8];
            #pragma unroll
            for (int ni = 0; ni < 4; ++ni) {
                const int d = ni * 16 + l15;
                short8 vf = *(const short8*)&Vs[cur][d * 132 + w * 32 + g * 8];
                acc[ni] = __builtin_amdgcn_mfma_f32_16x16x32_bf16(pf, vf, acc[ni], 0, 0, 0);
            }

            // ---- publish next tile ----
            if (it + 1 < iters) {
                #pragma unroll
                for (int u = 0; u < 4; ++u) {
                    const int slot = khalf * 4 + u;
                    *(short8*)&Ks[cur ^ 1][kvrow * 68 + slot * 8] = kr[u];
                    const int kv = vc * 8 + 32 * u;
                    *(short8*)&Vs[cur ^ 1][vd * 132 + kv] = vr[u];
                }
            }
            __syncthreads();
            cur ^= 1;
        }

        // ---- merge 4 wave-partials (flash-decoding combine) ----
        if (lane < 16) { Sm[w * 16 + lane] = m_w; Sl[w * 16 + lane] = l_w; }
        #pragma unroll
        for (int ni = 0; ni < 4; ++ni)
            #pragma unroll
            for (int r = 0; r < 4; ++r)
                Cs[w][(g * 4 + r) * 68 + ni * 16 + l15] = acc[ni][r];
        __syncthreads();

        {
            const int q = tid >> 4, d4 = (tid & 15) * 4;
            float mg = Sm[q];
            #pragma unroll
            for (int ww = 1; ww < 4; ++ww) mg = fmaxf(mg, Sm[ww * 16 + q]);
            f32x4 o = {0.f, 0.f, 0.f, 0.f};
            float lt = 0.0f;
            #pragma unroll
            for (int ww = 0; ww < 4; ++ww) {
                const float f = __expf(Sm[ww * 16 + q] - mg);
                lt += Sl[ww * 16 + q] * f;
                f32x4 c4 = *(const f32x4*)&Cs[ww][q * 68 + d4];
                o[0] += c4[0] * f; o[1] += c4[1] * f;
                o[2] += c4[2] * f; o[3] += c4[3] * f;
            }
            const float inv = 1.0f / lt;
            f32x4 res = {o[0]*inv, o[1]*inv, o[2]*inv, o[3]*inv};
            *(f32x4*)(out + ((size_t)b * SEQ + q0 + q) * HEAD + d4) = res;
        }
        __syncthreads();
    }
}

// ---------------------------------------------------------------------------
extern "C" void kernel_launch(void* const* d_in, const int* in_sizes, int n_in,
                              void* d_out, int out_size, void* d_ws, size_t ws_size,
                              hipStream_t stream) {
    const float* x  = (const float*)d_in[0];
    const float* Wq = (const float*)d_in[1];
    const float* bq = (const float*)d_in[2];
    const float* Wk = (const float*)d_in[3];
    const float* bk = (const float*)d_in[4];
    const float* Wv = (const float*)d_in[5];
    const float* bv = (const float*)d_in[6];

    unsigned short* Wt  = (unsigned short*)d_ws;                  // 384 KB
    unsigned short* qbp = Wt + (size_t)192 * D_MODEL;             // 1 MB
    unsigned short* kbp = qbp + (size_t)ROWS * HEAD;              // 1 MB
    unsigned short* vtp = kbp + (size_t)ROWS * HEAD;              // 1 MB (V^T)
    float* o = (float*)d_out;

    conv_w  <<<dim3(48),     dim3(256), 0, stream>>>(Wq, Wk, Wv, Wt);
    gemm_qkv<<<dim3(256),    dim3(256), 0, stream>>>(x, Wt, bq, bk, bv, qbp, kbp, vtp);
    attn_fwd<<<dim3(64, 4),  dim3(256), 0, stream>>>(qbp, kbp, vtp, o);
}